// Round 11
// baseline (1127.004 us; speedup 1.0000x reference)
//
#include <hip/hip_runtime.h>
#include <hip/hip_bf16.h>

// GCN: 3x GraphConv(sum-agg) + ELU, mean-pool, linear head, log_softmax.
// N=50000, E=400000, G=64, D_IN=200, D_HID=32. fp32 inputs/outputs.
// R11: 10 dispatches -> 5 (+1 memset) via lightweight in-kernel grid barriers
// among co-resident blocks (atomic arrive + relaxed spin + s_sleep). R10's
// lookback scan proved agent-scope spin works; R9's cg::grid.sync() disaster
// was cg overhead + full-fence-per-sync, NOT an argument against fusion.
// __threadfence (agent acq_rel -> L2 wb/inv on gfx950) brackets each barrier
// so plain-store producer -> consumer handoffs are coherent across XCDs.
// Numerics identical to R10 (bf16 MFMA layer-1, bf16 gather rows).

#define D_IN 200
#define N_GRAPHS 64

#define KP 232                 // padded K stride for bf16 Wt
#define KB 7                   // 7 k-blocks of 32
#define WT_ELEMS (64 * KP)     // 14848

#define NT 256
#define NSCB 196               // scan tiles: 196*256 = 50176 >= N
#define NB_BUILD 784           // build kernel blocks (<=4/CU via launch_bounds)
#define NB_LAYER 782           // agg/gemm kernel blocks (= 64-node tiles)

typedef __attribute__((ext_vector_type(8))) short bf16x8;
typedef __attribute__((ext_vector_type(4))) float f32x4;

__device__ __forceinline__ float4 elu4(float4 v) {
    float4 o;
    o.x = (v.x > 0.f) ? v.x : expm1f(v.x);
    o.y = (v.y > 0.f) ? v.y : expm1f(v.y);
    o.z = (v.z > 0.f) ? v.z : expm1f(v.z);
    o.w = (v.w > 0.f) ? v.w : expm1f(v.w);
    return o;
}

// Lightweight grid barrier among co-resident blocks. ctr must be zeroed
// before launch. __threadfence = agent acq_rel -> buffer_wbl2/inv, making
// plain stores before the barrier visible to all XCDs after it.
__device__ __forceinline__ void gbar(int* ctr, int target) {
    __threadfence();
    __syncthreads();
    if (threadIdx.x == 0) {
        __hip_atomic_fetch_add(ctr, 1, __ATOMIC_ACQ_REL, __HIP_MEMORY_SCOPE_AGENT);
        while (__hip_atomic_load(ctr, __ATOMIC_RELAXED, __HIP_MEMORY_SCOPE_AGENT) < target)
            __builtin_amdgcn_s_sleep(8);
    }
    __syncthreads();
    __threadfence();
}

// ================= build_all: count+pack | bar | scan | bar | fill+gemm1 =====
__global__ __launch_bounds__(NT, 4) void build_all(
        const int* __restrict__ src, const int* __restrict__ dst, int E,
        const float* __restrict__ X, const float* __restrict__ W1r,
        const float* __restrict__ W1l, __hip_bfloat16* __restrict__ Wt,
        int* __restrict__ cnt, int* __restrict__ bar, int* __restrict__ flag,
        int* __restrict__ partialSum, int* __restrict__ row_ptr,
        int* __restrict__ cursor, int* __restrict__ colIdx,
        __hip_bfloat16* __restrict__ yr16, float* __restrict__ yl, int N) {
    int tid = threadIdx.x, bid = blockIdx.x, nb = gridDim.x;
    int gtid = bid * NT + tid, gs = nb * NT;

    // ---- phase 0: count in-degrees + pack [W1r|W1l] -> bf16 Wt ----
    for (int e = gtid; e < E; e += gs) atomicAdd(&cnt[dst[e]], 1);
    for (int idx = gtid; idx < WT_ELEMS; idx += gs) {
        int n = idx / KP, k = idx % KP;
        float v = 0.f;
        if (k < D_IN) v = (n < 32) ? W1r[k * 32 + n] : W1l[k * 32 + (n - 32)];
        Wt[idx] = __float2bfloat16(v);
    }
    gbar(&bar[0], nb);

    // ---- phase 1: scan w/ lookback (blocks 0..NSCB-1), R10 body ----
    if (bid < NSCB) {
        __shared__ int s[NT];
        int tile = bid;
        int idx = tile * NT + tid;
        int v = (idx < N) ? cnt[idx] : 0;
        s[tid] = v;
        __syncthreads();
        for (int off = 1; off < NT; off <<= 1) {
            int u = (tid >= off) ? s[tid - off] : 0;
            __syncthreads();
            s[tid] += u;
            __syncthreads();
        }
        int excl = s[tid] - v;
        int total = s[NT - 1];
        if (tid == 0) {
            __hip_atomic_store(&partialSum[tile], total, __ATOMIC_RELAXED, __HIP_MEMORY_SCOPE_AGENT);
            __hip_atomic_store(&flag[tile], 1, __ATOMIC_RELEASE, __HIP_MEMORY_SCOPE_AGENT);
        }
        int ps = 0;
        if (tid < tile) {   // tile <= 195 < NT
            while (__hip_atomic_load(&flag[tid], __ATOMIC_ACQUIRE, __HIP_MEMORY_SCOPE_AGENT) == 0)
                __builtin_amdgcn_s_sleep(1);
            ps = __hip_atomic_load(&partialSum[tid], __ATOMIC_RELAXED, __HIP_MEMORY_SCOPE_AGENT);
        }
        __syncthreads();
        s[tid] = ps;
        __syncthreads();
        for (int off = 128; off > 0; off >>= 1) {
            if (tid < off) s[tid] += s[tid + off];
            __syncthreads();
        }
        int rp = s[0] + excl;
        if (idx < N) { row_ptr[idx] = rp; cursor[idx] = rp; }
        if (idx == N - 1) row_ptr[N] = rp + v;
    }
    gbar(&bar[1], nb);

    // ---- phase 2a: fill CSR (cursor now coherent via gbar's fence) ----
    for (int e = gtid; e < E; e += gs) {
        int p = atomicAdd(&cursor[dst[e]], 1);
        colIdx[p] = src[e];
    }
    // ---- phase 2b: layer-1 MFMA gemm, LDS-free (independent of CSR) ----
    {
        int lane = tid & 63, wv = tid >> 6;
        int l15 = lane & 15, q = lane >> 4;
        int ntile = (N + 63) >> 6;
        for (int tile = bid; tile < ntile; tile += nb) {
            long base = (long)tile * 64;
            long row = base + wv * 16 + l15;
            long rowc = (row < (long)N) ? row : (long)(N - 1);
            const float* xr = X + rowc * D_IN;
            bf16x8 a[KB];
#pragma unroll
            for (int kb = 0; kb < KB; ++kb) {
                int k0 = kb * 32 + q * 8;
                union { __hip_bfloat16 h[8]; bf16x8 v; } u;
                if (k0 + 8 <= D_IN) {
                    float4 v0 = *(const float4*)(xr + k0);
                    float4 v1 = *(const float4*)(xr + k0 + 4);
                    u.h[0] = __float2bfloat16(v0.x); u.h[1] = __float2bfloat16(v0.y);
                    u.h[2] = __float2bfloat16(v0.z); u.h[3] = __float2bfloat16(v0.w);
                    u.h[4] = __float2bfloat16(v1.x); u.h[5] = __float2bfloat16(v1.y);
                    u.h[6] = __float2bfloat16(v1.z); u.h[7] = __float2bfloat16(v1.w);
                } else {
#pragma unroll
                    for (int j = 0; j < 8; ++j) {
                        int k = k0 + j;
                        u.h[j] = __float2bfloat16(k < D_IN ? xr[k] : 0.f);
                    }
                }
                a[kb] = u.v;
            }
#pragma unroll
            for (int ns = 0; ns < 4; ++ns) {
                f32x4 acc = {0.f, 0.f, 0.f, 0.f};
#pragma unroll
                for (int kb = 0; kb < KB; ++kb) {
                    bf16x8 bfrag = *(const bf16x8*)(const void*)
                        (Wt + (ns * 16 + l15) * KP + kb * 32 + q * 8);
                    acc = __builtin_amdgcn_mfma_f32_16x16x32_bf16(a[kb], bfrag, acc, 0, 0, 0);
                }
                int col = ns * 16 + l15;
#pragma unroll
                for (int r = 0; r < 4; ++r) {
                    long node = base + wv * 16 + q * 4 + r;
                    if (node < N) {
                        if (col < 32) yr16[node * 32 + col] = __float2bfloat16(acc[r]);
                        else          yl[node * 32 + (col - 32)] = acc[r];
                    }
                }
            }
        }
    }
}

// ---- agg body (R10): 4 lanes/node, 16B bf16 gathers, unroll-8 masked ----
__device__ __forceinline__ void agg_body(const __hip_bfloat16* __restrict__ yr16,
                                         const float* __restrict__ yl,
                                         const int* __restrict__ row_ptr,
                                         const int* __restrict__ colIdx,
                                         const float* __restrict__ b,
                                         float* __restrict__ hout, int N,
                                         int bid, int nb, int tid) {
    int ln = tid & 3;
    int ntile = (N + 63) >> 6;
    const uint4* yv = (const uint4*)yr16;
    int f0 = ln * 8;
    float4 bA = *(const float4*)(b + f0);
    float4 bB = *(const float4*)(b + f0 + 4);
    for (int tile = bid; tile < ntile; tile += nb) {
        int node = tile * 64 + (tid >> 2);
        if (node >= N) continue;
        int s = row_ptr[node], e = row_ptr[node + 1];
        float4 rA = *(const float4*)(yl + (long)node * 32 + f0);
        float4 rB = *(const float4*)(yl + (long)node * 32 + f0 + 4);
        float acc[8] = {0.f, 0.f, 0.f, 0.f, 0.f, 0.f, 0.f, 0.f};
        for (int p = s; p < e; p += 8) {
            int jj[8]; float m[8];
#pragma unroll
            for (int i = 0; i < 8; ++i) {
                int pi = p + i;
                m[i] = (pi < e) ? 1.f : 0.f;
                pi = (pi < e) ? pi : (e - 1);
                jj[i] = colIdx[pi];
            }
            uint4 v[8];
#pragma unroll
            for (int i = 0; i < 8; ++i) v[i] = yv[(long)jj[i] * 4 + ln];
#pragma unroll
            for (int i = 0; i < 8; ++i) {
                uint d0 = v[i].x, d1 = v[i].y, d2 = v[i].z, d3 = v[i].w;
                acc[0] = fmaf(__uint_as_float(d0 << 16),         m[i], acc[0]);
                acc[1] = fmaf(__uint_as_float(d0 & 0xffff0000u), m[i], acc[1]);
                acc[2] = fmaf(__uint_as_float(d1 << 16),         m[i], acc[2]);
                acc[3] = fmaf(__uint_as_float(d1 & 0xffff0000u), m[i], acc[3]);
                acc[4] = fmaf(__uint_as_float(d2 << 16),         m[i], acc[4]);
                acc[5] = fmaf(__uint_as_float(d2 & 0xffff0000u), m[i], acc[5]);
                acc[6] = fmaf(__uint_as_float(d3 << 16),         m[i], acc[6]);
                acc[7] = fmaf(__uint_as_float(d3 & 0xffff0000u), m[i], acc[7]);
            }
        }
        float4 oA = elu4(make_float4(acc[0] + bA.x + rA.x, acc[1] + bA.y + rA.y,
                                     acc[2] + bA.z + rA.z, acc[3] + bA.w + rA.w));
        float4 oB = elu4(make_float4(acc[4] + bB.x + rB.x, acc[5] + bB.y + rB.y,
                                     acc[6] + bB.z + rB.z, acc[7] + bB.w + rB.w));
        *(float4*)(hout + (long)node * 32 + f0) = oA;
        *(float4*)(hout + (long)node * 32 + f0 + 4) = oB;
    }
}

// ---- K=32 fp32 gemm body (R10), LDS-staged, tile-strided ----
__device__ __forceinline__ void gemm32_body(const float* __restrict__ X,
                                            const float* __restrict__ Wr,
                                            const float* __restrict__ Wl,
                                            __hip_bfloat16* __restrict__ yr16,
                                            float* __restrict__ yl, int N,
                                            int bid, int nb, int tid, float4* xs) {
    int ntile = (N + 31) >> 5;
    const float4* X4 = (const float4*)X;
    long total4 = (long)N * 8;
    for (int tile = bid; tile < ntile; tile += nb) {
        long base = (long)tile * 32;
        __syncthreads();
        long g0 = base * 8;
        for (int i = tid; i < 32 * 8; i += NT) {
            long gi = g0 + i;
            xs[i] = (gi < total4) ? X4[gi] : make_float4(0.f, 0.f, 0.f, 0.f);
        }
        __syncthreads();
        int c = tid & 31;
        int nb2 = (tid >> 5) * 4;
        float accr[4] = {0.f, 0.f, 0.f, 0.f};
        float accl[4] = {0.f, 0.f, 0.f, 0.f};
        for (int k4 = 0; k4 < 8; ++k4) {
            float wr[4], wl[4];
#pragma unroll
            for (int qq = 0; qq < 4; ++qq) {
                wr[qq] = Wr[(k4 * 4 + qq) * 32 + c];
                wl[qq] = Wl[(k4 * 4 + qq) * 32 + c];
            }
#pragma unroll
            for (int i = 0; i < 4; ++i) {
                float4 xv = xs[(nb2 + i) * 8 + k4];
                accr[i] = fmaf(xv.x, wr[0], accr[i]); accr[i] = fmaf(xv.y, wr[1], accr[i]);
                accr[i] = fmaf(xv.z, wr[2], accr[i]); accr[i] = fmaf(xv.w, wr[3], accr[i]);
                accl[i] = fmaf(xv.x, wl[0], accl[i]); accl[i] = fmaf(xv.y, wl[1], accl[i]);
                accl[i] = fmaf(xv.z, wl[2], accl[i]); accl[i] = fmaf(xv.w, wl[3], accl[i]);
            }
        }
#pragma unroll
        for (int i = 0; i < 4; ++i) {
            long node = base + nb2 + i;
            if (node < N) {
                yr16[node * 32 + c] = __float2bfloat16(accr[i]);
                yl[node * 32 + c] = accl[i];
            }
        }
    }
}

// ================= agg_i | bar | gemm_{i+1} =================
__global__ __launch_bounds__(NT, 4) void agg_gemm(
        const __hip_bfloat16* __restrict__ yr16_in, const float* __restrict__ yl_in,
        const int* __restrict__ row_ptr, const int* __restrict__ colIdx,
        const float* __restrict__ b, float* __restrict__ h,
        const float* __restrict__ Wr, const float* __restrict__ Wl,
        __hip_bfloat16* __restrict__ yr16_out, float* __restrict__ yl_out,
        int* __restrict__ bar, int N) {
    __shared__ float4 xs[32 * 8];
    int tid = threadIdx.x, bid = blockIdx.x, nb = gridDim.x;
    agg_body(yr16_in, yl_in, row_ptr, colIdx, b, h, N, bid, nb, tid);
    gbar(bar, nb);
    gemm32_body(h, Wr, Wl, yr16_out, yl_out, N, bid, nb, tid, xs);
}

// ================= agg3 | bar | pool+head =================
__global__ __launch_bounds__(NT, 4) void agg3_pool(
        const __hip_bfloat16* __restrict__ yr16_in, const float* __restrict__ yl_in,
        const int* __restrict__ row_ptr, const int* __restrict__ colIdx,
        const float* __restrict__ b, float* __restrict__ h,
        const int* __restrict__ batch, const float* __restrict__ Wlin,
        const float* __restrict__ blin, float* __restrict__ out,
        int* __restrict__ bar, int N) {
    int tid = threadIdx.x, bid = blockIdx.x, nb = gridDim.x;
    agg_body(yr16_in, yl_in, row_ptr, colIdx, b, h, N, bid, nb, tid);
    gbar(bar, nb);
    if (bid >= N_GRAPHS) return;
    const float4* h4 = (const float4*)h;
    int g = bid;
    int lo = 0, hi = N;
    while (lo < hi) { int mid = (lo + hi) >> 1; if (batch[mid] < g) lo = mid + 1; else hi = mid; }
    int start = lo;
    hi = N;
    while (lo < hi) { int mid = (lo + hi) >> 1; if (batch[mid] < g + 1) lo = mid + 1; else hi = mid; }
    int end = lo;

    int f4 = tid & 7, r = tid >> 3;
    float4 acc = make_float4(0.f, 0.f, 0.f, 0.f);
    for (int i = start + r; i < end; i += 32) {
        float4 v = h4[(long)i * 8 + f4];
        acc.x += v.x; acc.y += v.y; acc.z += v.z; acc.w += v.w;
    }
    __shared__ float4 red[32][8];
    __shared__ float pooledS[32];
    red[r][f4] = acc;
    __syncthreads();
    if (r == 0) {
        float4 s = make_float4(0.f, 0.f, 0.f, 0.f);
#pragma unroll
        for (int r2 = 0; r2 < 32; ++r2) {
            float4 v = red[r2][f4];
            s.x += v.x; s.y += v.y; s.z += v.z; s.w += v.w;
        }
        float inv = 1.f / fmaxf((float)(end - start), 1.f);
        pooledS[f4 * 4 + 0] = s.x * inv;
        pooledS[f4 * 4 + 1] = s.y * inv;
        pooledS[f4 * 4 + 2] = s.z * inv;
        pooledS[f4 * 4 + 3] = s.w * inv;
    }
    __syncthreads();
    if (tid == 0) {
        float c0 = blin[0], c1 = blin[1];
        for (int k = 0; k < 32; ++k) {
            float pk = pooledS[k];
            c0 += pk * Wlin[k * 2 + 0];
            c1 += pk * Wlin[k * 2 + 1];
        }
        float m = fmaxf(c0, c1);
        float lse = m + logf(expf(c0 - m) + expf(c1 - m));
        out[g * 2 + 0] = c0 - lse;
        out[g * 2 + 1] = c1 - lse;
    }
}

extern "C" void kernel_launch(void* const* d_in, const int* in_sizes, int n_in,
                              void* d_out, int out_size, void* d_ws, size_t ws_size,
                              hipStream_t stream) {
    const float* x     = (const float*)d_in[0];
    const int*   eidx  = (const int*)d_in[1];
    const int*   batch = (const int*)d_in[3];
    const float* W1r = (const float*)d_in[4];
    const float* W1l = (const float*)d_in[5];
    const float* b1  = (const float*)d_in[6];
    const float* W2r = (const float*)d_in[7];
    const float* W2l = (const float*)d_in[8];
    const float* b2  = (const float*)d_in[9];
    const float* W3r = (const float*)d_in[10];
    const float* W3l = (const float*)d_in[11];
    const float* b3  = (const float*)d_in[12];
    const float* Wlin = (const float*)d_in[13];
    const float* blin = (const float*)d_in[14];
    float* out = (float*)d_out;

    const int N = in_sizes[0] / D_IN;  // 50000
    const int E = in_sizes[1] / 2;     // 400000
    const int* src = eidx;
    const int* dst = eidx + E;

    char* w = (char*)d_ws;
    auto alloc = [&](size_t bytes) -> void* {
        void* p = (void*)w;
        w += (bytes + 255) & ~(size_t)255;
        return p;
    };
    // zero region: cnt + bar + flag + partial (single memset covers all)
    char* zbase = w;
    int* cnt     = (int*)alloc((size_t)N * 4);
    int* bar     = (int*)alloc((size_t)16 * 4);       // bar[0..4] used
    int* flag    = (int*)alloc((size_t)NSCB * 4);
    int* partial = (int*)alloc((size_t)NSCB * 4);
    size_t zbytes = (size_t)(w - zbase);
    // non-zeroed
    int* row_ptr = (int*)alloc((size_t)(N + 1) * 4);
    int* cursor  = (int*)alloc((size_t)(N + 1) * 4);
    int* colIdx  = (int*)alloc((size_t)E * 4);
    __hip_bfloat16* Wt    = (__hip_bfloat16*)alloc((size_t)WT_ELEMS * 2);
    __hip_bfloat16* yr16A = (__hip_bfloat16*)alloc((size_t)N * 32 * 2);
    __hip_bfloat16* yr16B = (__hip_bfloat16*)alloc((size_t)N * 32 * 2);
    float* ylA = (float*)alloc((size_t)N * 32 * 4);
    float* ylB = (float*)alloc((size_t)N * 32 * 4);
    float* hA  = (float*)alloc((size_t)N * 32 * 4);

    hipMemsetAsync(zbase, 0, zbytes, stream);

    build_all<<<NB_BUILD, NT, 0, stream>>>(src, dst, E, x, W1r, W1l, Wt,
                                           cnt, bar, flag, partial,
                                           row_ptr, cursor, colIdx, yr16A, ylA, N);
    agg_gemm<<<NB_LAYER, NT, 0, stream>>>(yr16A, ylA, row_ptr, colIdx, b1, hA,
                                          W2r, W2l, yr16B, ylB, &bar[2], N);
    agg_gemm<<<NB_LAYER, NT, 0, stream>>>(yr16B, ylB, row_ptr, colIdx, b2, hA,
                                          W3r, W3l, yr16A, ylA, &bar[3], N);
    agg3_pool<<<NB_LAYER, NT, 0, stream>>>(yr16A, ylA, row_ptr, colIdx, b3, hA,
                                           batch, Wlin, blin, out, &bar[4], N);
}

// Round 12
// 232.412 us; speedup vs baseline: 4.8492x; 4.8492x over previous
//
#include <hip/hip_runtime.h>
#include <hip/hip_bf16.h>

// GCN: 3x GraphConv(sum-agg) + ELU, mean-pool, linear head, log_softmax.
// N=50000, E=400000, G=64, D_IN=200, D_HID=32. fp32 inputs/outputs.
// R12 = revert to R10 (233.8us, best verified). Evidence log:
//  - R9: cooperative grid.sync() single-kernel = 1520us (6.5x slower).
//  - R11: custom in-kernel barriers (atomic arrive + spin + threadfence)
//    = 1127us; build_all alone 365us vs ~25us as separate dispatches.
//  => On MI355X, kernel-boundary dispatch (~8-10us) IS the cheapest grid
//     barrier; per-thread agent-scope fences are ruinous. Multi-kernel
//     structure is structurally optimal here. Lookback scan (per-tile
//     fine-grained waits, mostly-ready) remains fine.
// Structure: matmul-first algebra (segment_sum(x[src])@Wr ==
// segment_sum((x@Wr)[src])), CSR pull (no float atomics), bf16 MFMA layer-1,
// bf16 gather rows, unroll-8 masked agg, fused fill+gemm1, fused pool+head.

#define D_IN 200
#define N_GRAPHS 64

#define KP 232                 // padded K stride for bf16 Wt
#define KB 7                   // 7 k-blocks of 32
#define WT_ELEMS (64 * KP)     // 14848

#define NT 256
#define NSCB 196               // scan tiles: 196*256 = 50176 >= N

typedef __attribute__((ext_vector_type(8))) short bf16x8;
typedef __attribute__((ext_vector_type(4))) float f32x4;

__device__ __forceinline__ float4 elu4(float4 v) {
    float4 o;
    o.x = (v.x > 0.f) ? v.x : expm1f(v.x);
    o.y = (v.y > 0.f) ? v.y : expm1f(v.y);
    o.z = (v.z > 0.f) ? v.z : expm1f(v.z);
    o.w = (v.w > 0.f) ? v.w : expm1f(v.w);
    return o;
}

// ---------------- count in-degrees + pack [W1r|W1l] -> bf16 Wt ----------------
__global__ __launch_bounds__(NT) void count_pack(const int* __restrict__ dst,
                                                 int* __restrict__ cnt, int E,
                                                 const float* __restrict__ Wr,
                                                 const float* __restrict__ Wl,
                                                 __hip_bfloat16* __restrict__ Wt, int egrid) {
    int blk = blockIdx.x;
    if (blk < egrid) {
        int e = blk * NT + threadIdx.x;
        if (e < E) atomicAdd(&cnt[dst[e]], 1);
    } else {
        int idx = (blk - egrid) * NT + threadIdx.x;
        if (idx < WT_ELEMS) {
            int n = idx / KP, k = idx % KP;
            float v = 0.f;
            if (k < D_IN) v = (n < 32) ? Wr[k * 32 + n] : Wl[k * 32 + (n - 32)];
            Wt[idx] = __float2bfloat16(v);
        }
    }
}

// ---------------- single-kernel scan w/ lookback (196 co-resident blocks) ----
// Fine-grained per-predecessor waits (mostly already satisfied) — NOT an
// all-arrive barrier; measured fast (R10).
__global__ __launch_bounds__(NT) void scan_fused(const int* __restrict__ cnt,
                                                 int* __restrict__ row_ptr,
                                                 int* __restrict__ cursor,
                                                 int* __restrict__ partialSum,
                                                 int* __restrict__ flag, int N) {
    __shared__ int s[NT];
    int tile = blockIdx.x, tid = threadIdx.x;
    int idx = tile * NT + tid;
    int v = (idx < N) ? cnt[idx] : 0;
    s[tid] = v;
    __syncthreads();
    for (int off = 1; off < NT; off <<= 1) {
        int u = (tid >= off) ? s[tid - off] : 0;
        __syncthreads();
        s[tid] += u;
        __syncthreads();
    }
    int excl = s[tid] - v;
    int total = s[NT - 1];
    if (tid == 0) {
        __hip_atomic_store(&partialSum[tile], total, __ATOMIC_RELAXED, __HIP_MEMORY_SCOPE_AGENT);
        __hip_atomic_store(&flag[tile], 1, __ATOMIC_RELEASE, __HIP_MEMORY_SCOPE_AGENT);
    }
    int ps = 0;
    if (tid < tile) {   // tile <= 195 < NT: one predecessor per thread
        while (__hip_atomic_load(&flag[tid], __ATOMIC_ACQUIRE, __HIP_MEMORY_SCOPE_AGENT) == 0) {}
        ps = __hip_atomic_load(&partialSum[tid], __ATOMIC_RELAXED, __HIP_MEMORY_SCOPE_AGENT);
    }
    __syncthreads();
    s[tid] = ps;
    __syncthreads();
    for (int off = 128; off > 0; off >>= 1) {
        if (tid < off) s[tid] += s[tid + off];
        __syncthreads();
    }
    int rp = s[0] + excl;
    if (idx < N) { row_ptr[idx] = rp; cursor[idx] = rp; }
    if (idx == N - 1) row_ptr[N] = rp + v;
}

// ---------------- fill CSR + layer-1 MFMA gemm (fused, independent) ----------
__global__ __launch_bounds__(NT) void fill_gemm1(const int* __restrict__ src,
                                                 const int* __restrict__ dst,
                                                 int* __restrict__ cursor,
                                                 int* __restrict__ colIdx, int E,
                                                 const float* __restrict__ X,
                                                 const __hip_bfloat16* __restrict__ Wt,
                                                 __hip_bfloat16* __restrict__ yr16,
                                                 float* __restrict__ yl, int N) {
    int tid = threadIdx.x, bid = blockIdx.x, nb = gridDim.x;
    for (int e = bid * NT + tid; e < E; e += nb * NT) {
        int p = atomicAdd(&cursor[dst[e]], 1);
        colIdx[p] = src[e];
    }
    int lane = tid & 63, wv = tid >> 6;
    int l15 = lane & 15, q = lane >> 4;
    int ntile = (N + 63) >> 6;
    for (int tile = bid; tile < ntile; tile += nb) {
        long base = (long)tile * 64;
        long row = base + wv * 16 + l15;
        long rowc = (row < (long)N) ? row : (long)(N - 1);
        const float* xr = X + rowc * D_IN;
        bf16x8 a[KB];
#pragma unroll
        for (int kb = 0; kb < KB; ++kb) {
            int k0 = kb * 32 + q * 8;
            union { __hip_bfloat16 h[8]; bf16x8 v; } u;
            if (k0 + 8 <= D_IN) {
                float4 v0 = *(const float4*)(xr + k0);
                float4 v1 = *(const float4*)(xr + k0 + 4);
                u.h[0] = __float2bfloat16(v0.x); u.h[1] = __float2bfloat16(v0.y);
                u.h[2] = __float2bfloat16(v0.z); u.h[3] = __float2bfloat16(v0.w);
                u.h[4] = __float2bfloat16(v1.x); u.h[5] = __float2bfloat16(v1.y);
                u.h[6] = __float2bfloat16(v1.z); u.h[7] = __float2bfloat16(v1.w);
            } else {
#pragma unroll
                for (int j = 0; j < 8; ++j) {
                    int k = k0 + j;
                    u.h[j] = __float2bfloat16(k < D_IN ? xr[k] : 0.f);
                }
            }
            a[kb] = u.v;
        }
#pragma unroll
        for (int ns = 0; ns < 4; ++ns) {
            f32x4 acc = {0.f, 0.f, 0.f, 0.f};
#pragma unroll
            for (int kb = 0; kb < KB; ++kb) {
                bf16x8 bfrag = *(const bf16x8*)(const void*)
                    (Wt + (ns * 16 + l15) * KP + kb * 32 + q * 8);
                acc = __builtin_amdgcn_mfma_f32_16x16x32_bf16(a[kb], bfrag, acc, 0, 0, 0);
            }
            int col = ns * 16 + l15;
#pragma unroll
            for (int r = 0; r < 4; ++r) {
                long node = base + wv * 16 + q * 4 + r;
                if (node < N) {
                    if (col < 32) yr16[node * 32 + col] = __float2bfloat16(acc[r]);
                    else          yl[node * 32 + (col - 32)] = acc[r];
                }
            }
        }
    }
}

// ---------------- aggregate (CSR pull of bf16 rows) + bias + root + ELU ------
// 4 lanes/node (each 16B = 8 bf16 feats), 64 nodes/block. Unroll-8 masked.
__global__ __launch_bounds__(NT) void agg_elu_k(const __hip_bfloat16* __restrict__ yr16,
                                                const float* __restrict__ yl,
                                                const int* __restrict__ row_ptr,
                                                const int* __restrict__ colIdx,
                                                const float* __restrict__ b,
                                                float* __restrict__ hout, int N) {
    int tid = threadIdx.x;
    int ln = tid & 3;                       // 16B chunk within 64B row
    int node = blockIdx.x * 64 + (tid >> 2);
    if (node >= N) return;
    const uint4* yv = (const uint4*)yr16;   // row = 4 x uint4
    int s = row_ptr[node], e = row_ptr[node + 1];
    int f0 = ln * 8;
    float4 bA = *(const float4*)(b + f0);
    float4 bB = *(const float4*)(b + f0 + 4);
    float4 rA = *(const float4*)(yl + (long)node * 32 + f0);
    float4 rB = *(const float4*)(yl + (long)node * 32 + f0 + 4);
    float acc[8] = {0.f, 0.f, 0.f, 0.f, 0.f, 0.f, 0.f, 0.f};
    for (int p = s; p < e; p += 8) {
        int jj[8]; float m[8];
#pragma unroll
        for (int i = 0; i < 8; ++i) {
            int pi = p + i;
            m[i] = (pi < e) ? 1.f : 0.f;
            pi = (pi < e) ? pi : (e - 1);
            jj[i] = colIdx[pi];
        }
        uint4 v[8];
#pragma unroll
        for (int i = 0; i < 8; ++i) v[i] = yv[(long)jj[i] * 4 + ln];
#pragma unroll
        for (int i = 0; i < 8; ++i) {
            uint d0 = v[i].x, d1 = v[i].y, d2 = v[i].z, d3 = v[i].w;
            acc[0] = fmaf(__uint_as_float(d0 << 16),          m[i], acc[0]);
            acc[1] = fmaf(__uint_as_float(d0 & 0xffff0000u),  m[i], acc[1]);
            acc[2] = fmaf(__uint_as_float(d1 << 16),          m[i], acc[2]);
            acc[3] = fmaf(__uint_as_float(d1 & 0xffff0000u),  m[i], acc[3]);
            acc[4] = fmaf(__uint_as_float(d2 << 16),          m[i], acc[4]);
            acc[5] = fmaf(__uint_as_float(d2 & 0xffff0000u),  m[i], acc[5]);
            acc[6] = fmaf(__uint_as_float(d3 << 16),          m[i], acc[6]);
            acc[7] = fmaf(__uint_as_float(d3 & 0xffff0000u),  m[i], acc[7]);
        }
    }
    float4 oA = elu4(make_float4(acc[0] + bA.x + rA.x, acc[1] + bA.y + rA.y,
                                 acc[2] + bA.z + rA.z, acc[3] + bA.w + rA.w));
    float4 oB = elu4(make_float4(acc[4] + bB.x + rB.x, acc[5] + bB.y + rB.y,
                                 acc[6] + bB.z + rB.z, acc[7] + bB.w + rB.w));
    *(float4*)(hout + (long)node * 32 + f0) = oA;
    *(float4*)(hout + (long)node * 32 + f0 + 4) = oB;
}

// ---------------- fp32 K=32 gemm (layers 2,3); yr written bf16 ----------------
__global__ __launch_bounds__(NT) void gemm_xw(const float* __restrict__ X,
                                              const float* __restrict__ Wr,
                                              const float* __restrict__ Wl,
                                              __hip_bfloat16* __restrict__ yr16,
                                              float* __restrict__ yl, int N) {
    __shared__ float4 xs[32 * 8];
    int t = threadIdx.x;
    long base = (long)blockIdx.x * 32;
    const float4* X4 = (const float4*)X;
    long total4 = (long)N * 8;
    long g0 = base * 8;
    for (int i = t; i < 32 * 8; i += NT) {
        long gi = g0 + i;
        xs[i] = (gi < total4) ? X4[gi] : make_float4(0.f, 0.f, 0.f, 0.f);
    }
    __syncthreads();

    int c = t & 31;
    int nb2 = (t >> 5) * 4;
    float accr[4] = {0.f, 0.f, 0.f, 0.f};
    float accl[4] = {0.f, 0.f, 0.f, 0.f};
    for (int k4 = 0; k4 < 8; ++k4) {
        float wr[4], wl[4];
#pragma unroll
        for (int qq = 0; qq < 4; ++qq) {
            wr[qq] = Wr[(k4 * 4 + qq) * 32 + c];
            wl[qq] = Wl[(k4 * 4 + qq) * 32 + c];
        }
#pragma unroll
        for (int i = 0; i < 4; ++i) {
            float4 xv = xs[(nb2 + i) * 8 + k4];
            accr[i] = fmaf(xv.x, wr[0], accr[i]); accr[i] = fmaf(xv.y, wr[1], accr[i]);
            accr[i] = fmaf(xv.z, wr[2], accr[i]); accr[i] = fmaf(xv.w, wr[3], accr[i]);
            accl[i] = fmaf(xv.x, wl[0], accl[i]); accl[i] = fmaf(xv.y, wl[1], accl[i]);
            accl[i] = fmaf(xv.z, wl[2], accl[i]); accl[i] = fmaf(xv.w, wl[3], accl[i]);
        }
    }
#pragma unroll
    for (int i = 0; i < 4; ++i) {
        long node = base + nb2 + i;
        if (node < N) {
            yr16[node * 32 + c] = __float2bfloat16(accr[i]);
            yl[node * 32 + c] = accl[i];
        }
    }
}

// ---------------- mean pool + linear head + log_softmax ----------------
__global__ __launch_bounds__(NT) void pool_head(const float4* __restrict__ h4,
                                                const int* __restrict__ batch,
                                                const float* __restrict__ Wlin,
                                                const float* __restrict__ blin,
                                                float* __restrict__ out, int N) {
    int g = blockIdx.x;
    int lo = 0, hi = N;
    while (lo < hi) { int mid = (lo + hi) >> 1; if (batch[mid] < g) lo = mid + 1; else hi = mid; }
    int start = lo;
    hi = N;
    while (lo < hi) { int mid = (lo + hi) >> 1; if (batch[mid] < g + 1) lo = mid + 1; else hi = mid; }
    int end = lo;

    int f4 = threadIdx.x & 7, r = threadIdx.x >> 3;
    float4 acc = make_float4(0.f, 0.f, 0.f, 0.f);
    for (int i = start + r; i < end; i += 32) {
        float4 v = h4[(long)i * 8 + f4];
        acc.x += v.x; acc.y += v.y; acc.z += v.z; acc.w += v.w;
    }
    __shared__ float4 red[32][8];
    __shared__ float pooledS[32];
    red[r][f4] = acc;
    __syncthreads();
    if (r == 0) {
        float4 s = make_float4(0.f, 0.f, 0.f, 0.f);
#pragma unroll
        for (int r2 = 0; r2 < 32; ++r2) {
            float4 v = red[r2][f4];
            s.x += v.x; s.y += v.y; s.z += v.z; s.w += v.w;
        }
        float inv = 1.f / fmaxf((float)(end - start), 1.f);
        pooledS[f4 * 4 + 0] = s.x * inv;
        pooledS[f4 * 4 + 1] = s.y * inv;
        pooledS[f4 * 4 + 2] = s.z * inv;
        pooledS[f4 * 4 + 3] = s.w * inv;
    }
    __syncthreads();
    if (threadIdx.x == 0) {
        float c0 = blin[0], c1 = blin[1];
        for (int k = 0; k < 32; ++k) {
            float pk = pooledS[k];
            c0 += pk * Wlin[k * 2 + 0];
            c1 += pk * Wlin[k * 2 + 1];
        }
        float m = fmaxf(c0, c1);
        float lse = m + logf(expf(c0 - m) + expf(c1 - m));
        out[g * 2 + 0] = c0 - lse;
        out[g * 2 + 1] = c1 - lse;
    }
}

extern "C" void kernel_launch(void* const* d_in, const int* in_sizes, int n_in,
                              void* d_out, int out_size, void* d_ws, size_t ws_size,
                              hipStream_t stream) {
    const float* x     = (const float*)d_in[0];
    const int*   eidx  = (const int*)d_in[1];
    const int*   batch = (const int*)d_in[3];
    const float* W1r = (const float*)d_in[4];
    const float* W1l = (const float*)d_in[5];
    const float* b1  = (const float*)d_in[6];
    const float* W2r = (const float*)d_in[7];
    const float* W2l = (const float*)d_in[8];
    const float* b2  = (const float*)d_in[9];
    const float* W3r = (const float*)d_in[10];
    const float* W3l = (const float*)d_in[11];
    const float* b3  = (const float*)d_in[12];
    const float* Wlin = (const float*)d_in[13];
    const float* blin = (const float*)d_in[14];
    float* out = (float*)d_out;

    const int N = in_sizes[0] / D_IN;  // 50000
    const int E = in_sizes[1] / 2;     // 400000
    const int* src = eidx;
    const int* dst = eidx + E;

    char* w = (char*)d_ws;
    auto alloc = [&](size_t bytes) -> void* {
        void* p = (void*)w;
        w += (bytes + 255) & ~(size_t)255;
        return p;
    };
    int* cnt     = (int*)alloc((size_t)N * 4);
    int* flag    = (int*)alloc((size_t)256 * 4);        // adjacent to cnt: one memset
    int* row_ptr = (int*)alloc((size_t)(N + 1) * 4);
    int* cursor  = (int*)alloc((size_t)(N + 1) * 4);
    int* colIdx  = (int*)alloc((size_t)E * 4);
    int* partial = (int*)alloc((size_t)256 * 4);
    __hip_bfloat16* Wt    = (__hip_bfloat16*)alloc((size_t)WT_ELEMS * 2);
    __hip_bfloat16* yr16A = (__hip_bfloat16*)alloc((size_t)N * 32 * 2);
    __hip_bfloat16* yr16B = (__hip_bfloat16*)alloc((size_t)N * 32 * 2);
    float* ylA = (float*)alloc((size_t)N * 32 * 4);
    float* ylB = (float*)alloc((size_t)N * 32 * 4);
    float* hA  = (float*)alloc((size_t)N * 32 * 4);

    // zero cnt + flag (adjacent allocations) in one memset
    hipMemsetAsync(cnt, 0, (((size_t)N * 4 + 255) & ~(size_t)255) + 1024, stream);

    int egrid = (E + NT - 1) / NT;           // 1563
    int wgrid = (WT_ELEMS + NT - 1) / NT;    // 58
    int t64   = (N + 63) / 64;               // 782
    int t32   = (N + 31) / 32;               // 1563

    count_pack<<<egrid + wgrid, NT, 0, stream>>>(dst, cnt, E, W1r, W1l, Wt, egrid);
    scan_fused<<<NSCB, NT, 0, stream>>>(cnt, row_ptr, cursor, partial, flag, N);
    fill_gemm1<<<t64, NT, 0, stream>>>(src, dst, cursor, colIdx, E, x, Wt, yr16A, ylA, N);
    agg_elu_k<<<t64, NT, 0, stream>>>(yr16A, ylA, row_ptr, colIdx, b1, hA, N);
    gemm_xw<<<t32, NT, 0, stream>>>(hA, W2r, W2l, yr16B, ylB, N);
    agg_elu_k<<<t64, NT, 0, stream>>>(yr16B, ylB, row_ptr, colIdx, b2, hA, N);
    gemm_xw<<<t32, NT, 0, stream>>>(hA, W3r, W3l, yr16A, ylA, N);
    agg_elu_k<<<t64, NT, 0, stream>>>(yr16A, ylA, row_ptr, colIdx, b3, hA, N);
    pool_head<<<N_GRAPHS, NT, 0, stream>>>((const float4*)hA, batch, Wlin, blin, out, N);
}

// Round 13
// 222.668 us; speedup vs baseline: 5.0614x; 1.0438x over previous
//
#include <hip/hip_runtime.h>
#include <hip/hip_bf16.h>

// GCN: 3x GraphConv(sum-agg) + ELU, mean-pool, linear head, log_softmax.
// N=50000, E=400000, G=64, D_IN=200, D_HID=32. fp32 inputs/outputs.
// R13 = R12 + rank trick: count_pack's atomicAdd already yields each edge's
// rank within its destination -- store it, and CSR fill becomes atomic-free
// (colIdx[row_ptr[dst]+rank] = src). R12's fill_gemm1 was 42.6us with all
// pipes idle: 400K cursor RMWs = ~128 serialized atomics per cache line.
// Evidence log (structure): R9 coop grid.sync = 1520us, R11 custom in-kernel
// barriers = 1127us => kernel-boundary dispatch is the cheapest grid barrier
// on MI355X; multi-kernel structure is optimal. Lookback scan (fine-grained
// per-tile waits) measured fast.

#define D_IN 200
#define N_GRAPHS 64

#define KP 232                 // padded K stride for bf16 Wt
#define KB 7                   // 7 k-blocks of 32
#define WT_ELEMS (64 * KP)     // 14848

#define NT 256
#define NSCB 196               // scan tiles: 196*256 = 50176 >= N

typedef __attribute__((ext_vector_type(8))) short bf16x8;
typedef __attribute__((ext_vector_type(4))) float f32x4;

__device__ __forceinline__ float4 elu4(float4 v) {
    float4 o;
    o.x = (v.x > 0.f) ? v.x : expm1f(v.x);
    o.y = (v.y > 0.f) ? v.y : expm1f(v.y);
    o.z = (v.z > 0.f) ? v.z : expm1f(v.z);
    o.w = (v.w > 0.f) ? v.w : expm1f(v.w);
    return o;
}

// ------- count in-degrees (store per-edge rank!) + pack [W1r|W1l] -> bf16 ----
__global__ __launch_bounds__(NT) void count_pack(const int* __restrict__ dst,
                                                 int* __restrict__ cnt,
                                                 int* __restrict__ rank, int E,
                                                 const float* __restrict__ Wr,
                                                 const float* __restrict__ Wl,
                                                 __hip_bfloat16* __restrict__ Wt, int egrid) {
    int blk = blockIdx.x;
    if (blk < egrid) {
        int e = blk * NT + threadIdx.x;
        if (e < E) rank[e] = atomicAdd(&cnt[dst[e]], 1);   // rank = free byproduct
    } else {
        int idx = (blk - egrid) * NT + threadIdx.x;
        if (idx < WT_ELEMS) {
            int n = idx / KP, k = idx % KP;
            float v = 0.f;
            if (k < D_IN) v = (n < 32) ? Wr[k * 32 + n] : Wl[k * 32 + (n - 32)];
            Wt[idx] = __float2bfloat16(v);
        }
    }
}

// ---------------- single-kernel scan w/ lookback (196 co-resident blocks) ----
__global__ __launch_bounds__(NT) void scan_fused(const int* __restrict__ cnt,
                                                 int* __restrict__ row_ptr,
                                                 int* __restrict__ partialSum,
                                                 int* __restrict__ flag, int N) {
    __shared__ int s[NT];
    int tile = blockIdx.x, tid = threadIdx.x;
    int idx = tile * NT + tid;
    int v = (idx < N) ? cnt[idx] : 0;
    s[tid] = v;
    __syncthreads();
    for (int off = 1; off < NT; off <<= 1) {
        int u = (tid >= off) ? s[tid - off] : 0;
        __syncthreads();
        s[tid] += u;
        __syncthreads();
    }
    int excl = s[tid] - v;
    int total = s[NT - 1];
    if (tid == 0) {
        __hip_atomic_store(&partialSum[tile], total, __ATOMIC_RELAXED, __HIP_MEMORY_SCOPE_AGENT);
        __hip_atomic_store(&flag[tile], 1, __ATOMIC_RELEASE, __HIP_MEMORY_SCOPE_AGENT);
    }
    int ps = 0;
    if (tid < tile) {   // tile <= 195 < NT: one predecessor per thread
        while (__hip_atomic_load(&flag[tid], __ATOMIC_ACQUIRE, __HIP_MEMORY_SCOPE_AGENT) == 0) {}
        ps = __hip_atomic_load(&partialSum[tid], __ATOMIC_RELAXED, __HIP_MEMORY_SCOPE_AGENT);
    }
    __syncthreads();
    s[tid] = ps;
    __syncthreads();
    for (int off = 128; off > 0; off >>= 1) {
        if (tid < off) s[tid] += s[tid + off];
        __syncthreads();
    }
    int rp = s[0] + excl;
    if (idx < N) row_ptr[idx] = rp;
    if (idx == N - 1) row_ptr[N] = rp + v;
}

// ------- CSR fill (atomic-free via rank) + layer-1 MFMA gemm (fused) ---------
__global__ __launch_bounds__(NT) void fill_gemm1(const int* __restrict__ src,
                                                 const int* __restrict__ dst,
                                                 const int* __restrict__ rank,
                                                 const int* __restrict__ row_ptr,
                                                 int* __restrict__ colIdx, int E,
                                                 const float* __restrict__ X,
                                                 const __hip_bfloat16* __restrict__ Wt,
                                                 __hip_bfloat16* __restrict__ yr16,
                                                 float* __restrict__ yl, int N) {
    int tid = threadIdx.x, bid = blockIdx.x, nb = gridDim.x;
    for (int e = bid * NT + tid; e < E; e += nb * NT) {
        int d = dst[e];
        colIdx[row_ptr[d] + rank[e]] = src[e];   // no RMW: short load chain
    }
    int lane = tid & 63, wv = tid >> 6;
    int l15 = lane & 15, q = lane >> 4;
    int ntile = (N + 63) >> 6;
    for (int tile = bid; tile < ntile; tile += nb) {
        long base = (long)tile * 64;
        long row = base + wv * 16 + l15;
        long rowc = (row < (long)N) ? row : (long)(N - 1);
        const float* xr = X + rowc * D_IN;
        bf16x8 a[KB];
#pragma unroll
        for (int kb = 0; kb < KB; ++kb) {
            int k0 = kb * 32 + q * 8;
            union { __hip_bfloat16 h[8]; bf16x8 v; } u;
            if (k0 + 8 <= D_IN) {
                float4 v0 = *(const float4*)(xr + k0);
                float4 v1 = *(const float4*)(xr + k0 + 4);
                u.h[0] = __float2bfloat16(v0.x); u.h[1] = __float2bfloat16(v0.y);
                u.h[2] = __float2bfloat16(v0.z); u.h[3] = __float2bfloat16(v0.w);
                u.h[4] = __float2bfloat16(v1.x); u.h[5] = __float2bfloat16(v1.y);
                u.h[6] = __float2bfloat16(v1.z); u.h[7] = __float2bfloat16(v1.w);
            } else {
#pragma unroll
                for (int j = 0; j < 8; ++j) {
                    int k = k0 + j;
                    u.h[j] = __float2bfloat16(k < D_IN ? xr[k] : 0.f);
                }
            }
            a[kb] = u.v;
        }
#pragma unroll
        for (int ns = 0; ns < 4; ++ns) {
            f32x4 acc = {0.f, 0.f, 0.f, 0.f};
#pragma unroll
            for (int kb = 0; kb < KB; ++kb) {
                bf16x8 bfrag = *(const bf16x8*)(const void*)
                    (Wt + (ns * 16 + l15) * KP + kb * 32 + q * 8);
                acc = __builtin_amdgcn_mfma_f32_16x16x32_bf16(a[kb], bfrag, acc, 0, 0, 0);
            }
            int col = ns * 16 + l15;
#pragma unroll
            for (int r = 0; r < 4; ++r) {
                long node = base + wv * 16 + q * 4 + r;
                if (node < N) {
                    if (col < 32) yr16[node * 32 + col] = __float2bfloat16(acc[r]);
                    else          yl[node * 32 + (col - 32)] = acc[r];
                }
            }
        }
    }
}

// ---------------- aggregate (CSR pull of bf16 rows) + bias + root + ELU ------
__global__ __launch_bounds__(NT) void agg_elu_k(const __hip_bfloat16* __restrict__ yr16,
                                                const float* __restrict__ yl,
                                                const int* __restrict__ row_ptr,
                                                const int* __restrict__ colIdx,
                                                const float* __restrict__ b,
                                                float* __restrict__ hout, int N) {
    int tid = threadIdx.x;
    int ln = tid & 3;                       // 16B chunk within 64B row
    int node = blockIdx.x * 64 + (tid >> 2);
    if (node >= N) return;
    const uint4* yv = (const uint4*)yr16;   // row = 4 x uint4
    int s = row_ptr[node], e = row_ptr[node + 1];
    int f0 = ln * 8;
    float4 bA = *(const float4*)(b + f0);
    float4 bB = *(const float4*)(b + f0 + 4);
    float4 rA = *(const float4*)(yl + (long)node * 32 + f0);
    float4 rB = *(const float4*)(yl + (long)node * 32 + f0 + 4);
    float acc[8] = {0.f, 0.f, 0.f, 0.f, 0.f, 0.f, 0.f, 0.f};
    for (int p = s; p < e; p += 8) {
        int jj[8]; float m[8];
#pragma unroll
        for (int i = 0; i < 8; ++i) {
            int pi = p + i;
            m[i] = (pi < e) ? 1.f : 0.f;
            pi = (pi < e) ? pi : (e - 1);
            jj[i] = colIdx[pi];
        }
        uint4 v[8];
#pragma unroll
        for (int i = 0; i < 8; ++i) v[i] = yv[(long)jj[i] * 4 + ln];
#pragma unroll
        for (int i = 0; i < 8; ++i) {
            uint d0 = v[i].x, d1 = v[i].y, d2 = v[i].z, d3 = v[i].w;
            acc[0] = fmaf(__uint_as_float(d0 << 16),          m[i], acc[0]);
            acc[1] = fmaf(__uint_as_float(d0 & 0xffff0000u),  m[i], acc[1]);
            acc[2] = fmaf(__uint_as_float(d1 << 16),          m[i], acc[2]);
            acc[3] = fmaf(__uint_as_float(d1 & 0xffff0000u),  m[i], acc[3]);
            acc[4] = fmaf(__uint_as_float(d2 << 16),          m[i], acc[4]);
            acc[5] = fmaf(__uint_as_float(d2 & 0xffff0000u),  m[i], acc[5]);
            acc[6] = fmaf(__uint_as_float(d3 << 16),          m[i], acc[6]);
            acc[7] = fmaf(__uint_as_float(d3 & 0xffff0000u),  m[i], acc[7]);
        }
    }
    float4 oA = elu4(make_float4(acc[0] + bA.x + rA.x, acc[1] + bA.y + rA.y,
                                 acc[2] + bA.z + rA.z, acc[3] + bA.w + rA.w));
    float4 oB = elu4(make_float4(acc[4] + bB.x + rB.x, acc[5] + bB.y + rB.y,
                                 acc[6] + bB.z + rB.z, acc[7] + bB.w + rB.w));
    *(float4*)(hout + (long)node * 32 + f0) = oA;
    *(float4*)(hout + (long)node * 32 + f0 + 4) = oB;
}

// ---------------- fp32 K=32 gemm (layers 2,3); yr written bf16 ----------------
__global__ __launch_bounds__(NT) void gemm_xw(const float* __restrict__ X,
                                              const float* __restrict__ Wr,
                                              const float* __restrict__ Wl,
                                              __hip_bfloat16* __restrict__ yr16,
                                              float* __restrict__ yl, int N) {
    __shared__ float4 xs[32 * 8];
    int t = threadIdx.x;
    long base = (long)blockIdx.x * 32;
    const float4* X4 = (const float4*)X;
    long total4 = (long)N * 8;
    long g0 = base * 8;
    for (int i = t; i < 32 * 8; i += NT) {
        long gi = g0 + i;
        xs[i] = (gi < total4) ? X4[gi] : make_float4(0.f, 0.f, 0.f, 0.f);
    }
    __syncthreads();

    int c = t & 31;
    int nb2 = (t >> 5) * 4;
    float accr[4] = {0.f, 0.f, 0.f, 0.f};
    float accl[4] = {0.f, 0.f, 0.f, 0.f};
    for (int k4 = 0; k4 < 8; ++k4) {
        float wr[4], wl[4];
#pragma unroll
        for (int qq = 0; qq < 4; ++qq) {
            wr[qq] = Wr[(k4 * 4 + qq) * 32 + c];
            wl[qq] = Wl[(k4 * 4 + qq) * 32 + c];
        }
#pragma unroll
        for (int i = 0; i < 4; ++i) {
            float4 xv = xs[(nb2 + i) * 8 + k4];
            accr[i] = fmaf(xv.x, wr[0], accr[i]); accr[i] = fmaf(xv.y, wr[1], accr[i]);
            accr[i] = fmaf(xv.z, wr[2], accr[i]); accr[i] = fmaf(xv.w, wr[3], accr[i]);
            accl[i] = fmaf(xv.x, wl[0], accl[i]); accl[i] = fmaf(xv.y, wl[1], accl[i]);
            accl[i] = fmaf(xv.z, wl[2], accl[i]); accl[i] = fmaf(xv.w, wl[3], accl[i]);
        }
    }
#pragma unroll
    for (int i = 0; i < 4; ++i) {
        long node = base + nb2 + i;
        if (node < N) {
            yr16[node * 32 + c] = __float2bfloat16(accr[i]);
            yl[node * 32 + c] = accl[i];
        }
    }
}

// ---------------- mean pool + linear head + log_softmax ----------------
__global__ __launch_bounds__(NT) void pool_head(const float4* __restrict__ h4,
                                                const int* __restrict__ batch,
                                                const float* __restrict__ Wlin,
                                                const float* __restrict__ blin,
                                                float* __restrict__ out, int N) {
    int g = blockIdx.x;
    int lo = 0, hi = N;
    while (lo < hi) { int mid = (lo + hi) >> 1; if (batch[mid] < g) lo = mid + 1; else hi = mid; }
    int start = lo;
    hi = N;
    while (lo < hi) { int mid = (lo + hi) >> 1; if (batch[mid] < g + 1) lo = mid + 1; else hi = mid; }
    int end = lo;

    int f4 = threadIdx.x & 7, r = threadIdx.x >> 3;
    float4 acc = make_float4(0.f, 0.f, 0.f, 0.f);
    for (int i = start + r; i < end; i += 32) {
        float4 v = h4[(long)i * 8 + f4];
        acc.x += v.x; acc.y += v.y; acc.z += v.z; acc.w += v.w;
    }
    __shared__ float4 red[32][8];
    __shared__ float pooledS[32];
    red[r][f4] = acc;
    __syncthreads();
    if (r == 0) {
        float4 s = make_float4(0.f, 0.f, 0.f, 0.f);
#pragma unroll
        for (int r2 = 0; r2 < 32; ++r2) {
            float4 v = red[r2][f4];
            s.x += v.x; s.y += v.y; s.z += v.z; s.w += v.w;
        }
        float inv = 1.f / fmaxf((float)(end - start), 1.f);
        pooledS[f4 * 4 + 0] = s.x * inv;
        pooledS[f4 * 4 + 1] = s.y * inv;
        pooledS[f4 * 4 + 2] = s.z * inv;
        pooledS[f4 * 4 + 3] = s.w * inv;
    }
    __syncthreads();
    if (threadIdx.x == 0) {
        float c0 = blin[0], c1 = blin[1];
        for (int k = 0; k < 32; ++k) {
            float pk = pooledS[k];
            c0 += pk * Wlin[k * 2 + 0];
            c1 += pk * Wlin[k * 2 + 1];
        }
        float m = fmaxf(c0, c1);
        float lse = m + logf(expf(c0 - m) + expf(c1 - m));
        out[g * 2 + 0] = c0 - lse;
        out[g * 2 + 1] = c1 - lse;
    }
}

extern "C" void kernel_launch(void* const* d_in, const int* in_sizes, int n_in,
                              void* d_out, int out_size, void* d_ws, size_t ws_size,
                              hipStream_t stream) {
    const float* x     = (const float*)d_in[0];
    const int*   eidx  = (const int*)d_in[1];
    const int*   batch = (const int*)d_in[3];
    const float* W1r = (const float*)d_in[4];
    const float* W1l = (const float*)d_in[5];
    const float* b1  = (const float*)d_in[6];
    const float* W2r = (const float*)d_in[7];
    const float* W2l = (const float*)d_in[8];
    const float* b2  = (const float*)d_in[9];
    const float* W3r = (const float*)d_in[10];
    const float* W3l = (const float*)d_in[11];
    const float* b3  = (const float*)d_in[12];
    const float* Wlin = (const float*)d_in[13];
    const float* blin = (const float*)d_in[14];
    float* out = (float*)d_out;

    const int N = in_sizes[0] / D_IN;  // 50000
    const int E = in_sizes[1] / 2;     // 400000
    const int* src = eidx;
    const int* dst = eidx + E;

    char* w = (char*)d_ws;
    auto alloc = [&](size_t bytes) -> void* {
        void* p = (void*)w;
        w += (bytes + 255) & ~(size_t)255;
        return p;
    };
    int* cnt     = (int*)alloc((size_t)N * 4);
    int* flag    = (int*)alloc((size_t)256 * 4);        // adjacent to cnt: one memset
    int* rank    = (int*)alloc((size_t)E * 4);
    int* row_ptr = (int*)alloc((size_t)(N + 1) * 4);
    int* colIdx  = (int*)alloc((size_t)E * 4);
    int* partial = (int*)alloc((size_t)256 * 4);
    __hip_bfloat16* Wt    = (__hip_bfloat16*)alloc((size_t)WT_ELEMS * 2);
    __hip_bfloat16* yr16A = (__hip_bfloat16*)alloc((size_t)N * 32 * 2);
    __hip_bfloat16* yr16B = (__hip_bfloat16*)alloc((size_t)N * 32 * 2);
    float* ylA = (float*)alloc((size_t)N * 32 * 4);
    float* ylB = (float*)alloc((size_t)N * 32 * 4);
    float* hA  = (float*)alloc((size_t)N * 32 * 4);

    // zero cnt + flag (adjacent allocations) in one memset
    hipMemsetAsync(cnt, 0, (((size_t)N * 4 + 255) & ~(size_t)255) + 1024, stream);

    int egrid = (E + NT - 1) / NT;           // 1563
    int wgrid = (WT_ELEMS + NT - 1) / NT;    // 58
    int t64   = (N + 63) / 64;               // 782
    int t32   = (N + 31) / 32;               // 1563

    count_pack<<<egrid + wgrid, NT, 0, stream>>>(dst, cnt, rank, E, W1r, W1l, Wt, egrid);
    scan_fused<<<NSCB, NT, 0, stream>>>(cnt, row_ptr, partial, flag, N);
    fill_gemm1<<<t64, NT, 0, stream>>>(src, dst, rank, row_ptr, colIdx, E, x, Wt, yr16A, ylA, N);
    agg_elu_k<<<t64, NT, 0, stream>>>(yr16A, ylA, row_ptr, colIdx, b1, hA, N);
    gemm_xw<<<t32, NT, 0, stream>>>(hA, W2r, W2l, yr16B, ylB, N);
    agg_elu_k<<<t64, NT, 0, stream>>>(yr16B, ylB, row_ptr, colIdx, b2, hA, N);
    gemm_xw<<<t32, NT, 0, stream>>>(hA, W3r, W3l, yr16A, ylA, N);
    agg_elu_k<<<t64, NT, 0, stream>>>(yr16A, ylA, row_ptr, colIdx, b3, hA, N);
    pool_head<<<N_GRAPHS, NT, 0, stream>>>((const float4*)hA, batch, Wlin, blin, out, N);
}

// Round 14
// 199.380 us; speedup vs baseline: 5.6526x; 1.1168x over previous
//
#include <hip/hip_runtime.h>
#include <hip/hip_bf16.h>

// GCN: 3x GraphConv(sum-agg) + ELU, mean-pool, linear head, log_softmax.
// N=50000, E=400000, G=64, D_IN=200, D_HID=32. fp32 inputs/outputs.
// R14 = R13 + agg_i/gemm_{i+1} fusion via per-node dependency (no grid sync
// needed: gemm of node n needs only h[n], produced by the same block's agg).
// R4's fp32 fused version died at VGPR=160 / 8% occupancy; here the K=32 gemm
// is ONE bf16 MFMA per 16x16 tile (h staged to LDS as bf16, W2/W3 pre-packed)
// so the gemm phase adds ~30 VGPR and ~4 MFMAs/wave. Cuts 2 dispatch
// boundaries + 2 h round-trips + both gemm_xw kernels.
// Evidence log: R9 coop=1520us, R11 in-kernel barriers=1127us => dispatch
// boundary IS the cheapest grid barrier on MI355X. R13 rank-trick: fill
// atomic-free. Harness ws-poison fill (~43us) is fixed cost.

#define D_IN 200
#define N_GRAPHS 64

#define KP 232                 // padded K stride for bf16 Wt (layer 1)
#define KB 7                   // 7 k-blocks of 32
#define WT_ELEMS (64 * KP)     // 14848
#define W23_ELEMS 2048         // 64 x 32 per layer

#define NT 256
#define NSCB 196               // scan tiles: 196*256 = 50176 >= N
#define HS_STR 40              // LDS h-row stride in bf16 (pad 32->40: kills 8-way)

typedef __attribute__((ext_vector_type(8))) short bf16x8;
typedef __attribute__((ext_vector_type(4))) float f32x4;

__device__ __forceinline__ float4 elu4(float4 v) {
    float4 o;
    o.x = (v.x > 0.f) ? v.x : expm1f(v.x);
    o.y = (v.y > 0.f) ? v.y : expm1f(v.y);
    o.z = (v.z > 0.f) ? v.z : expm1f(v.z);
    o.w = (v.w > 0.f) ? v.w : expm1f(v.w);
    return o;
}

// ------- count in-degrees (store per-edge rank) + pack W1/W2/W3 -> bf16 ------
__global__ __launch_bounds__(NT) void count_pack(const int* __restrict__ dst,
                                                 int* __restrict__ cnt,
                                                 int* __restrict__ rank, int E,
                                                 const float* __restrict__ W1r,
                                                 const float* __restrict__ W1l,
                                                 const float* __restrict__ W2r,
                                                 const float* __restrict__ W2l,
                                                 const float* __restrict__ W3r,
                                                 const float* __restrict__ W3l,
                                                 __hip_bfloat16* __restrict__ Wt,
                                                 __hip_bfloat16* __restrict__ Wt2,
                                                 __hip_bfloat16* __restrict__ Wt3,
                                                 int egrid, int wgrid) {
    int blk = blockIdx.x;
    if (blk < egrid) {
        int e = blk * NT + threadIdx.x;
        if (e < E) rank[e] = atomicAdd(&cnt[dst[e]], 1);   // rank = free byproduct
    } else if (blk < egrid + wgrid) {
        int idx = (blk - egrid) * NT + threadIdx.x;
        if (idx < WT_ELEMS) {
            int n = idx / KP, k = idx % KP;
            float v = 0.f;
            if (k < D_IN) v = (n < 32) ? W1r[k * 32 + n] : W1l[k * 32 + (n - 32)];
            Wt[idx] = __float2bfloat16(v);
        }
    } else {
        int idx = (blk - egrid - wgrid) * NT + threadIdx.x;  // 0..4095
        if (idx < 2 * W23_ELEMS) {
            int which = idx >> 11;          // 0: layer2, 1: layer3
            int j = idx & 2047;             // n*32 + k
            int n = j >> 5, k = j & 31;
            const float* Wr = which ? W3r : W2r;
            const float* Wl = which ? W3l : W2l;
            float v = (n < 32) ? Wr[k * 32 + n] : Wl[k * 32 + (n - 32)];
            (which ? Wt3 : Wt2)[j] = __float2bfloat16(v);
        }
    }
}

// ---------------- single-kernel scan w/ lookback (196 co-resident blocks) ----
__global__ __launch_bounds__(NT) void scan_fused(const int* __restrict__ cnt,
                                                 int* __restrict__ row_ptr,
                                                 int* __restrict__ partialSum,
                                                 int* __restrict__ flag, int N) {
    __shared__ int s[NT];
    int tile = blockIdx.x, tid = threadIdx.x;
    int idx = tile * NT + tid;
    int v = (idx < N) ? cnt[idx] : 0;
    s[tid] = v;
    __syncthreads();
    for (int off = 1; off < NT; off <<= 1) {
        int u = (tid >= off) ? s[tid - off] : 0;
        __syncthreads();
        s[tid] += u;
        __syncthreads();
    }
    int excl = s[tid] - v;
    int total = s[NT - 1];
    if (tid == 0) {
        __hip_atomic_store(&partialSum[tile], total, __ATOMIC_RELAXED, __HIP_MEMORY_SCOPE_AGENT);
        __hip_atomic_store(&flag[tile], 1, __ATOMIC_RELEASE, __HIP_MEMORY_SCOPE_AGENT);
    }
    int ps = 0;
    if (tid < tile) {   // tile <= 195 < NT: one predecessor per thread
        while (__hip_atomic_load(&flag[tid], __ATOMIC_ACQUIRE, __HIP_MEMORY_SCOPE_AGENT) == 0) {}
        ps = __hip_atomic_load(&partialSum[tid], __ATOMIC_RELAXED, __HIP_MEMORY_SCOPE_AGENT);
    }
    __syncthreads();
    s[tid] = ps;
    __syncthreads();
    for (int off = 128; off > 0; off >>= 1) {
        if (tid < off) s[tid] += s[tid + off];
        __syncthreads();
    }
    int rp = s[0] + excl;
    if (idx < N) row_ptr[idx] = rp;
    if (idx == N - 1) row_ptr[N] = rp + v;
}

// ------- CSR fill (atomic-free via rank) + layer-1 MFMA gemm (fused) ---------
__global__ __launch_bounds__(NT) void fill_gemm1(const int* __restrict__ src,
                                                 const int* __restrict__ dst,
                                                 const int* __restrict__ rank,
                                                 const int* __restrict__ row_ptr,
                                                 int* __restrict__ colIdx, int E,
                                                 const float* __restrict__ X,
                                                 const __hip_bfloat16* __restrict__ Wt,
                                                 __hip_bfloat16* __restrict__ yr16,
                                                 float* __restrict__ yl, int N) {
    int tid = threadIdx.x, bid = blockIdx.x, nb = gridDim.x;
    for (int e = bid * NT + tid; e < E; e += nb * NT) {
        int d = dst[e];
        colIdx[row_ptr[d] + rank[e]] = src[e];   // no RMW: short load chain
    }
    int lane = tid & 63, wv = tid >> 6;
    int l15 = lane & 15, q = lane >> 4;
    int ntile = (N + 63) >> 6;
    for (int tile = bid; tile < ntile; tile += nb) {
        long base = (long)tile * 64;
        long row = base + wv * 16 + l15;
        long rowc = (row < (long)N) ? row : (long)(N - 1);
        const float* xr = X + rowc * D_IN;
        bf16x8 a[KB];
#pragma unroll
        for (int kb = 0; kb < KB; ++kb) {
            int k0 = kb * 32 + q * 8;
            union { __hip_bfloat16 h[8]; bf16x8 v; } u;
            if (k0 + 8 <= D_IN) {
                float4 v0 = *(const float4*)(xr + k0);
                float4 v1 = *(const float4*)(xr + k0 + 4);
                u.h[0] = __float2bfloat16(v0.x); u.h[1] = __float2bfloat16(v0.y);
                u.h[2] = __float2bfloat16(v0.z); u.h[3] = __float2bfloat16(v0.w);
                u.h[4] = __float2bfloat16(v1.x); u.h[5] = __float2bfloat16(v1.y);
                u.h[6] = __float2bfloat16(v1.z); u.h[7] = __float2bfloat16(v1.w);
            } else {
#pragma unroll
                for (int j = 0; j < 8; ++j) {
                    int k = k0 + j;
                    u.h[j] = __float2bfloat16(k < D_IN ? xr[k] : 0.f);
                }
            }
            a[kb] = u.v;
        }
#pragma unroll
        for (int ns = 0; ns < 4; ++ns) {
            f32x4 acc = {0.f, 0.f, 0.f, 0.f};
#pragma unroll
            for (int kb = 0; kb < KB; ++kb) {
                bf16x8 bfrag = *(const bf16x8*)(const void*)
                    (Wt + (ns * 16 + l15) * KP + kb * 32 + q * 8);
                acc = __builtin_amdgcn_mfma_f32_16x16x32_bf16(a[kb], bfrag, acc, 0, 0, 0);
            }
            int col = ns * 16 + l15;
#pragma unroll
            for (int r = 0; r < 4; ++r) {
                long node = base + wv * 16 + q * 4 + r;
                if (node < N) {
                    if (col < 32) yr16[node * 32 + col] = __float2bfloat16(acc[r]);
                    else          yl[node * 32 + (col - 32)] = acc[r];
                }
            }
        }
    }
}

// ---- agg body: CSR pull of bf16 rows + bias + root + ELU -> two float4 ----
__device__ __forceinline__ void agg_node(const __hip_bfloat16* __restrict__ yr16,
                                         const float* __restrict__ yl,
                                         const int* __restrict__ row_ptr,
                                         const int* __restrict__ colIdx,
                                         const float* __restrict__ b,
                                         int node, int ln, float4& oA, float4& oB) {
    const uint4* yv = (const uint4*)yr16;   // row = 4 x uint4
    int s = row_ptr[node], e = row_ptr[node + 1];
    int f0 = ln * 8;
    float4 bA = *(const float4*)(b + f0);
    float4 bB = *(const float4*)(b + f0 + 4);
    float4 rA = *(const float4*)(yl + (long)node * 32 + f0);
    float4 rB = *(const float4*)(yl + (long)node * 32 + f0 + 4);
    float acc[8] = {0.f, 0.f, 0.f, 0.f, 0.f, 0.f, 0.f, 0.f};
    for (int p = s; p < e; p += 8) {
        int jj[8]; float m[8];
#pragma unroll
        for (int i = 0; i < 8; ++i) {
            int pi = p + i;
            m[i] = (pi < e) ? 1.f : 0.f;
            pi = (pi < e) ? pi : (e - 1);
            jj[i] = colIdx[pi];
        }
        uint4 v[8];
#pragma unroll
        for (int i = 0; i < 8; ++i) v[i] = yv[(long)jj[i] * 4 + ln];
#pragma unroll
        for (int i = 0; i < 8; ++i) {
            uint d0 = v[i].x, d1 = v[i].y, d2 = v[i].z, d3 = v[i].w;
            acc[0] = fmaf(__uint_as_float(d0 << 16),          m[i], acc[0]);
            acc[1] = fmaf(__uint_as_float(d0 & 0xffff0000u),  m[i], acc[1]);
            acc[2] = fmaf(__uint_as_float(d1 << 16),          m[i], acc[2]);
            acc[3] = fmaf(__uint_as_float(d1 & 0xffff0000u),  m[i], acc[3]);
            acc[4] = fmaf(__uint_as_float(d2 << 16),          m[i], acc[4]);
            acc[5] = fmaf(__uint_as_float(d2 & 0xffff0000u),  m[i], acc[5]);
            acc[6] = fmaf(__uint_as_float(d3 << 16),          m[i], acc[6]);
            acc[7] = fmaf(__uint_as_float(d3 & 0xffff0000u),  m[i], acc[7]);
        }
    }
    oA = elu4(make_float4(acc[0] + bA.x + rA.x, acc[1] + bA.y + rA.y,
                          acc[2] + bA.z + rA.z, acc[3] + bA.w + rA.w));
    oB = elu4(make_float4(acc[4] + bB.x + rB.x, acc[5] + bB.y + rB.y,
                          acc[6] + bB.z + rB.z, acc[7] + bB.w + rB.w));
}

// ------- fused agg_i + gemm_{i+1}: h lives only in LDS (bf16), K=32 MFMA -----
// Per-node dependency only: block aggs its 64 nodes -> LDS, __syncthreads,
// then 4 MFMAs/wave compute y = h @ [Wr|Wl]. No grid sync anywhere.
__global__ __launch_bounds__(NT) void agg_gemm_mfma(
        const __hip_bfloat16* __restrict__ yr16_in, const float* __restrict__ yl_in,
        const int* __restrict__ row_ptr, const int* __restrict__ colIdx,
        const float* __restrict__ b, const __hip_bfloat16* __restrict__ Wt2,
        __hip_bfloat16* __restrict__ yr16_out, float* __restrict__ yl_out, int N) {
    __shared__ __hip_bfloat16 hs[64 * HS_STR];
    int tid = threadIdx.x;
    int ln = tid & 3;
    int nl = tid >> 2;                       // node-local 0..63
    long base = (long)blockIdx.x * 64;
    int node = (int)base + nl;
    union { __hip_bfloat16 h[8]; float4 v; } u;
    if (node < N) {
        float4 oA, oB;
        agg_node(yr16_in, yl_in, row_ptr, colIdx, b, node, ln, oA, oB);
        u.h[0] = __float2bfloat16(oA.x); u.h[1] = __float2bfloat16(oA.y);
        u.h[2] = __float2bfloat16(oA.z); u.h[3] = __float2bfloat16(oA.w);
        u.h[4] = __float2bfloat16(oB.x); u.h[5] = __float2bfloat16(oB.y);
        u.h[6] = __float2bfloat16(oB.z); u.h[7] = __float2bfloat16(oB.w);
    } else {
        u.v = make_float4(0.f, 0.f, 0.f, 0.f);
    }
    *(float4*)(&hs[nl * HS_STR + ln * 8]) = u.v;   // 16B aligned (HS_STR*2=80)
    __syncthreads();

    int lane = tid & 63, wv = tid >> 6;
    int l15 = lane & 15, q = lane >> 4;
    bf16x8 a = *(const bf16x8*)(const void*)(&hs[(wv * 16 + l15) * HS_STR + q * 8]);
#pragma unroll
    for (int ns = 0; ns < 4; ++ns) {
        f32x4 acc = {0.f, 0.f, 0.f, 0.f};
        bf16x8 bfrag = *(const bf16x8*)(const void*)(Wt2 + (ns * 16 + l15) * 32 + q * 8);
        acc = __builtin_amdgcn_mfma_f32_16x16x32_bf16(a, bfrag, acc, 0, 0, 0);
        int col = ns * 16 + l15;
#pragma unroll
        for (int r = 0; r < 4; ++r) {
            long nd = base + wv * 16 + q * 4 + r;
            if (nd < N) {
                if (col < 32) yr16_out[nd * 32 + col] = __float2bfloat16(acc[r]);
                else          yl_out[nd * 32 + (col - 32)] = acc[r];
            }
        }
    }
}

// ---------------- layer-3 agg -> fp32 h (for pool) ----------------
__global__ __launch_bounds__(NT) void agg_elu_k(const __hip_bfloat16* __restrict__ yr16,
                                                const float* __restrict__ yl,
                                                const int* __restrict__ row_ptr,
                                                const int* __restrict__ colIdx,
                                                const float* __restrict__ b,
                                                float* __restrict__ hout, int N) {
    int tid = threadIdx.x;
    int ln = tid & 3;
    int node = blockIdx.x * 64 + (tid >> 2);
    if (node >= N) return;
    float4 oA, oB;
    agg_node(yr16, yl, row_ptr, colIdx, b, node, ln, oA, oB);
    int f0 = ln * 8;
    *(float4*)(hout + (long)node * 32 + f0) = oA;
    *(float4*)(hout + (long)node * 32 + f0 + 4) = oB;
}

// ---------------- mean pool + linear head + log_softmax ----------------
__global__ __launch_bounds__(NT) void pool_head(const float4* __restrict__ h4,
                                                const int* __restrict__ batch,
                                                const float* __restrict__ Wlin,
                                                const float* __restrict__ blin,
                                                float* __restrict__ out, int N) {
    int g = blockIdx.x;
    int lo = 0, hi = N;
    while (lo < hi) { int mid = (lo + hi) >> 1; if (batch[mid] < g) lo = mid + 1; else hi = mid; }
    int start = lo;
    hi = N;
    while (lo < hi) { int mid = (lo + hi) >> 1; if (batch[mid] < g + 1) lo = mid + 1; else hi = mid; }
    int end = lo;

    int f4 = threadIdx.x & 7, r = threadIdx.x >> 3;
    float4 acc = make_float4(0.f, 0.f, 0.f, 0.f);
    for (int i = start + r; i < end; i += 32) {
        float4 v = h4[(long)i * 8 + f4];
        acc.x += v.x; acc.y += v.y; acc.z += v.z; acc.w += v.w;
    }
    __shared__ float4 red[32][8];
    __shared__ float pooledS[32];
    red[r][f4] = acc;
    __syncthreads();
    if (r == 0) {
        float4 s = make_float4(0.f, 0.f, 0.f, 0.f);
#pragma unroll
        for (int r2 = 0; r2 < 32; ++r2) {
            float4 v = red[r2][f4];
            s.x += v.x; s.y += v.y; s.z += v.z; s.w += v.w;
        }
        float inv = 1.f / fmaxf((float)(end - start), 1.f);
        pooledS[f4 * 4 + 0] = s.x * inv;
        pooledS[f4 * 4 + 1] = s.y * inv;
        pooledS[f4 * 4 + 2] = s.z * inv;
        pooledS[f4 * 4 + 3] = s.w * inv;
    }
    __syncthreads();
    if (threadIdx.x == 0) {
        float c0 = blin[0], c1 = blin[1];
        for (int k = 0; k < 32; ++k) {
            float pk = pooledS[k];
            c0 += pk * Wlin[k * 2 + 0];
            c1 += pk * Wlin[k * 2 + 1];
        }
        float m = fmaxf(c0, c1);
        float lse = m + logf(expf(c0 - m) + expf(c1 - m));
        out[g * 2 + 0] = c0 - lse;
        out[g * 2 + 1] = c1 - lse;
    }
}

extern "C" void kernel_launch(void* const* d_in, const int* in_sizes, int n_in,
                              void* d_out, int out_size, void* d_ws, size_t ws_size,
                              hipStream_t stream) {
    const float* x     = (const float*)d_in[0];
    const int*   eidx  = (const int*)d_in[1];
    const int*   batch = (const int*)d_in[3];
    const float* W1r = (const float*)d_in[4];
    const float* W1l = (const float*)d_in[5];
    const float* b1  = (const float*)d_in[6];
    const float* W2r = (const float*)d_in[7];
    const float* W2l = (const float*)d_in[8];
    const float* b2  = (const float*)d_in[9];
    const float* W3r = (const float*)d_in[10];
    const float* W3l = (const float*)d_in[11];
    const float* b3  = (const float*)d_in[12];
    const float* Wlin = (const float*)d_in[13];
    const float* blin = (const float*)d_in[14];
    float* out = (float*)d_out;

    const int N = in_sizes[0] / D_IN;  // 50000
    const int E = in_sizes[1] / 2;     // 400000
    const int* src = eidx;
    const int* dst = eidx + E;

    char* w = (char*)d_ws;
    auto alloc = [&](size_t bytes) -> void* {
        void* p = (void*)w;
        w += (bytes + 255) & ~(size_t)255;
        return p;
    };
    int* cnt     = (int*)alloc((size_t)N * 4);
    int* flag    = (int*)alloc((size_t)256 * 4);        // adjacent to cnt: one memset
    int* rank    = (int*)alloc((size_t)E * 4);
    int* row_ptr = (int*)alloc((size_t)(N + 1) * 4);
    int* colIdx  = (int*)alloc((size_t)E * 4);
    int* partial = (int*)alloc((size_t)256 * 4);
    __hip_bfloat16* Wt    = (__hip_bfloat16*)alloc((size_t)WT_ELEMS * 2);
    __hip_bfloat16* Wt2   = (__hip_bfloat16*)alloc((size_t)W23_ELEMS * 2);
    __hip_bfloat16* Wt3   = (__hip_bfloat16*)alloc((size_t)W23_ELEMS * 2);
    __hip_bfloat16* yr16A = (__hip_bfloat16*)alloc((size_t)N * 32 * 2);
    __hip_bfloat16* yr16B = (__hip_bfloat16*)alloc((size_t)N * 32 * 2);
    float* ylA = (float*)alloc((size_t)N * 32 * 4);
    float* ylB = (float*)alloc((size_t)N * 32 * 4);
    float* hA  = (float*)alloc((size_t)N * 32 * 4);

    // zero cnt + flag (adjacent allocations) in one memset
    hipMemsetAsync(cnt, 0, (((size_t)N * 4 + 255) & ~(size_t)255) + 1024, stream);

    int egrid = (E + NT - 1) / NT;           // 1563
    int wgrid = (WT_ELEMS + NT - 1) / NT;    // 58
    int w23g  = (2 * W23_ELEMS + NT - 1) / NT; // 16
    int t64   = (N + 63) / 64;               // 782

    count_pack<<<egrid + wgrid + w23g, NT, 0, stream>>>(
        dst, cnt, rank, E, W1r, W1l, W2r, W2l, W3r, W3l, Wt, Wt2, Wt3, egrid, wgrid);
    scan_fused<<<NSCB, NT, 0, stream>>>(cnt, row_ptr, partial, flag, N);
    fill_gemm1<<<t64, NT, 0, stream>>>(src, dst, rank, row_ptr, colIdx, E, x, Wt, yr16A, ylA, N);
    // agg1 + gemm2 (fused, per-node dep only)
    agg_gemm_mfma<<<t64, NT, 0, stream>>>(yr16A, ylA, row_ptr, colIdx, b1, Wt2,
                                          yr16B, ylB, N);
    // agg2 + gemm3
    agg_gemm_mfma<<<t64, NT, 0, stream>>>(yr16B, ylB, row_ptr, colIdx, b2, Wt3,
                                          yr16A, ylA, N);
    // agg3 -> fp32 h
    agg_elu_k<<<t64, NT, 0, stream>>>(yr16A, ylA, row_ptr, colIdx, b3, hA, N);
    pool_head<<<N_GRAPHS, NT, 0, stream>>>((const float4*)hA, batch, Wlin, blin, out, N);
}